// Round 2
// baseline (1090.710 us; speedup 1.0000x reference)
//
#include <hip/hip_runtime.h>
#include <hip/hip_bf16.h>
#include <math.h>

#define NIN 128
#define HC 128
#define NOUT 768
#define BM 64
#define BK 32

// ---------------- Kernel A: fused input GEMMs (q,k,v,skip), bf16 output ----------------
__global__ __launch_bounds__(256) void gemm_qkvs(
    const float* __restrict__ x,
    const float* __restrict__ Wq, const float* __restrict__ bq,
    const float* __restrict__ Wk, const float* __restrict__ bk,
    const float* __restrict__ Wv, const float* __restrict__ bv,
    const float* __restrict__ Wsk, const float* __restrict__ bsk,
    __hip_bfloat16* __restrict__ outbase, int N)
{
    const int wsel = blockIdx.y;
    const float* W; const float* b;
    switch (wsel) {
        case 0: W = Wq;  b = bq;  break;
        case 1: W = Wk;  b = bk;  break;
        case 2: W = Wv;  b = bv;  break;
        default: W = Wsk; b = bsk; break;
    }
    __hip_bfloat16* out = outbase + (size_t)wsel * (size_t)N * HC;

    __shared__ float xs[BM][36];
    __shared__ float wsh[BK][132];

    const int tid = threadIdx.x;
    const int ty = tid >> 4;            // 0..15
    const int tx = tid & 15;            // 0..15
    const int rowBase = blockIdx.x * BM;

    float acc[4][8];
    #pragma unroll
    for (int i = 0; i < 4; ++i)
        #pragma unroll
        for (int j = 0; j < 8; ++j) acc[i][j] = 0.f;

    for (int k0 = 0; k0 < NIN; k0 += BK) {
        {
            const int lr = tid >> 2;          // 0..63
            const int lc = (tid & 3) * 8;     // 0,8,16,24
            const int gr = rowBase + lr;
            float4 a0 = make_float4(0.f, 0.f, 0.f, 0.f), a1 = a0;
            if (gr < N) {
                const float4* xp = (const float4*)(x + (size_t)gr * NIN + k0 + lc);
                a0 = xp[0]; a1 = xp[1];
            }
            *(float4*)&xs[lr][lc]     = a0;
            *(float4*)&xs[lr][lc + 4] = a1;
        }
        {
            const int wr = tid >> 3;          // 0..31
            const int wc = (tid & 7) * 16;    // 0..112
            const float4* wp = (const float4*)(W + (size_t)(k0 + wr) * HC + wc);
            *(float4*)&wsh[wr][wc]      = wp[0];
            *(float4*)&wsh[wr][wc + 4]  = wp[1];
            *(float4*)&wsh[wr][wc + 8]  = wp[2];
            *(float4*)&wsh[wr][wc + 12] = wp[3];
        }
        __syncthreads();

        #pragma unroll 8
        for (int kk = 0; kk < BK; ++kk) {
            float a[4];
            #pragma unroll
            for (int i = 0; i < 4; ++i) a[i] = xs[ty * 4 + i][kk];
            float4 b0 = *(float4*)&wsh[kk][tx * 8];
            float4 b1 = *(float4*)&wsh[kk][tx * 8 + 4];
            float bb[8] = {b0.x, b0.y, b0.z, b0.w, b1.x, b1.y, b1.z, b1.w};
            #pragma unroll
            for (int i = 0; i < 4; ++i)
                #pragma unroll
                for (int j = 0; j < 8; ++j)
                    acc[i][j] = fmaf(a[i], bb[j], acc[i][j]);
        }
        __syncthreads();
    }

    float bb[8];
    #pragma unroll
    for (int j = 0; j < 8; ++j) bb[j] = b[tx * 8 + j];
    #pragma unroll
    for (int i = 0; i < 4; ++i) {
        const int r = rowBase + ty * 4 + i;
        if (r < N) {
            union { __hip_bfloat16 h[8]; uint4 u; } pack;
            #pragma unroll
            for (int j = 0; j < 8; ++j)
                pack.h[j] = __float2bfloat16(acc[i][j] + bb[j]);
            *(uint4*)&out[(size_t)r * HC + tx * 8] = pack.u;
        }
    }
}

// ---------------- Kernel B: fused edge attention + unnormalized aggregation ----------------
// One 64-lane wave per edge; lane owns channels (2*lane, 2*lane+1), head = lane>>4.
// Softmax max-shift skipped (exact identity); normalization deferred to gate_pool.
__global__ __launch_bounds__(256) void edge_fused(
    const __hip_bfloat16* __restrict__ q, const __hip_bfloat16* __restrict__ k,
    const __hip_bfloat16* __restrict__ v, const int* __restrict__ ei,
    float* __restrict__ den, float* __restrict__ agg, int E)
{
    const int e = (int)(((long long)blockIdx.x * 256 + threadIdx.x) >> 6);
    if (e >= E) return;
    const int lane = threadIdx.x & 63;
    const int s = ei[e];        // src
    const int d = ei[E + e];    // dst
    const int c = 2 * lane;

    const __hip_bfloat162 q2 = *(const __hip_bfloat162*)(q + (size_t)d * HC + c);
    const __hip_bfloat162 k2 = *(const __hip_bfloat162*)(k + (size_t)s * HC + c);
    const __hip_bfloat162 v2 = *(const __hip_bfloat162*)(v + (size_t)s * HC + c);

    float p = __bfloat162float(q2.x) * __bfloat162float(k2.x)
            + __bfloat162float(q2.y) * __bfloat162float(k2.y);
    // sum over the 16-lane group (= 32 channels = one head)
    p += __shfl_xor(p, 1, 64);
    p += __shfl_xor(p, 2, 64);
    p += __shfl_xor(p, 4, 64);
    p += __shfl_xor(p, 8, 64);

    const float ex = __expf(p * 0.17677669529663687f);   // 1/sqrt(32)
    if ((lane & 15) == 0)
        atomicAdd(den + (size_t)d * 4 + (lane >> 4), ex);
    atomicAdd(agg + (size_t)d * HC + c,     __bfloat162float(v2.x) * ex);
    atomicAdd(agg + (size_t)d * HC + c + 1, __bfloat162float(v2.y) * ex);
}

// ---------------- Kernel C: normalize + beta gate + LeakyReLU + graph pool ----------------
// One 64-lane wave per node (4 nodes per 256-thread block).
__global__ __launch_bounds__(256) void gate_pool(
    const float* __restrict__ agg, const __hip_bfloat16* __restrict__ skip,
    const float* __restrict__ den, const float* __restrict__ Wbeta,
    const int* __restrict__ batch,
    float* __restrict__ pooled, float* __restrict__ cnts, int N)
{
    const int n = blockIdx.x * 4 + (threadIdx.x >> 6);
    if (n >= N) return;
    const int lane = threadIdx.x & 63;
    const int c = 2 * lane;

    const float dn = den[(size_t)n * 4 + (lane >> 4)] + 1e-16f;
    const float o0 = agg[(size_t)n * HC + c]     / dn;
    const float o1 = agg[(size_t)n * HC + c + 1] / dn;
    const __hip_bfloat162 s2 = *(const __hip_bfloat162*)(skip + (size_t)n * HC + c);
    const float sk0 = __bfloat162float(s2.x);
    const float sk1 = __bfloat162float(s2.y);

    float part = o0 * Wbeta[c]     + sk0 * Wbeta[HC + c]     + (o0 - sk0) * Wbeta[2 * HC + c]
               + o1 * Wbeta[c + 1] + sk1 * Wbeta[HC + c + 1] + (o1 - sk1) * Wbeta[2 * HC + c + 1];
    #pragma unroll
    for (int m = 1; m < 64; m <<= 1) part += __shfl_xor(part, m, 64);

    const float beta = 1.f / (1.f + __expf(-part));
    float r0 = beta * sk0 + (1.f - beta) * o0;
    float r1 = beta * sk1 + (1.f - beta) * o1;
    r0 = (r0 >= 0.f) ? r0 : 0.01f * r0;
    r1 = (r1 >= 0.f) ? r1 : 0.01f * r1;

    const int g = batch[n];
    atomicAdd(pooled + (size_t)g * HC + c,     r0);
    atomicAdd(pooled + (size_t)g * HC + c + 1, r1);
    if (lane == 0) atomicAdd(cnts + g, 1.0f);
}

// ---------------- Kernel D: per-graph mean + final GEMM ----------------
__global__ __launch_bounds__(256) void final_gemm(
    const float* __restrict__ pooled, const float* __restrict__ cnts,
    const float* __restrict__ W2, const float* __restrict__ b2,
    float* __restrict__ out, int G)
{
    const int g = blockIdx.x;
    __shared__ float p[HC];
    const int t = threadIdx.x;
    if (t < HC) p[t] = pooled[(size_t)g * HC + t] / fmaxf(cnts[g], 1.0f);
    __syncthreads();
    for (int j = t; j < NOUT; j += 256) {
        float acc = b2[j];
        #pragma unroll 8
        for (int c = 0; c < HC; ++c) acc = fmaf(p[c], W2[(size_t)c * NOUT + j], acc);
        out[(size_t)g * NOUT + j] = acc;
    }
}

// ---------------- launch ----------------
extern "C" void kernel_launch(void* const* d_in, const int* in_sizes, int n_in,
                              void* d_out, int out_size, void* d_ws, size_t ws_size,
                              hipStream_t stream) {
    const float* x     = (const float*)d_in[0];
    const int*   ei    = (const int*)d_in[1];
    const int*   batch = (const int*)d_in[2];
    const float* Wq  = (const float*)d_in[3];  const float* bq  = (const float*)d_in[4];
    const float* Wk  = (const float*)d_in[5];  const float* bk  = (const float*)d_in[6];
    const float* Wv  = (const float*)d_in[7];  const float* bv  = (const float*)d_in[8];
    const float* Wsk = (const float*)d_in[9];  const float* bsk = (const float*)d_in[10];
    const float* Wbeta = (const float*)d_in[11];
    const float* W2  = (const float*)d_in[12]; const float* b2  = (const float*)d_in[13];

    const int N = in_sizes[0] / NIN;
    const int E = in_sizes[1] / 2;
    const int G = out_size / NOUT;

    char* ws = (char*)d_ws;
    const size_t nbQ = (size_t)N * HC * sizeof(__hip_bfloat16);   // 25.6 MB
    __hip_bfloat16* q    = (__hip_bfloat16*)(ws);
    __hip_bfloat16* kk_  = (__hip_bfloat16*)(ws + nbQ);
    __hip_bfloat16* vv   = (__hip_bfloat16*)(ws + 2 * nbQ);
    __hip_bfloat16* skip = (__hip_bfloat16*)(ws + 3 * nbQ);
    float* den    = (float*)(ws + 4 * nbQ);
    float* agg    = den + (size_t)N * 4;
    float* pooled = agg + (size_t)N * HC;
    float* cnts   = pooled + (size_t)G * HC;
    const size_t zeroBytes = ((size_t)N * 4 + (size_t)N * HC +
                              (size_t)G * HC + (size_t)G) * sizeof(float);

    hipMemsetAsync(den, 0, zeroBytes, stream);

    dim3 gA((N + BM - 1) / BM, 4);
    gemm_qkvs<<<gA, 256, 0, stream>>>(x, Wq, bq, Wk, bk, Wv, bv, Wsk, bsk, q, N);

    const int edgeBlocks = (int)(((long long)E * 64 + 255) / 256);
    edge_fused<<<edgeBlocks, 256, 0, stream>>>(q, kk_, vv, ei, den, agg, E);

    gate_pool<<<(N + 3) / 4, 256, 0, stream>>>(agg, skip, den, Wbeta, batch,
                                               pooled, cnts, N);

    final_gemm<<<G, 256, 0, stream>>>(pooled, cnts, W2, b2, (float*)d_out, G);
}

// Round 3
// 597.144 us; speedup vs baseline: 1.8265x; 1.8265x over previous
//
#include <hip/hip_runtime.h>
#include <hip/hip_bf16.h>
#include <math.h>

#define NIN 128
#define HC 128
#define NOUT 768
#define BM 64
#define BK 32

// ---------------- Kernel A: fused input GEMMs (q,k,v,skip), bf16 output ----------------
__global__ __launch_bounds__(256) void gemm_qkvs(
    const float* __restrict__ x,
    const float* __restrict__ Wq, const float* __restrict__ bq,
    const float* __restrict__ Wk, const float* __restrict__ bk,
    const float* __restrict__ Wv, const float* __restrict__ bv,
    const float* __restrict__ Wsk, const float* __restrict__ bsk,
    __hip_bfloat16* __restrict__ outbase, int N)
{
    const int wsel = blockIdx.y;
    const float* W; const float* b;
    switch (wsel) {
        case 0: W = Wq;  b = bq;  break;
        case 1: W = Wk;  b = bk;  break;
        case 2: W = Wv;  b = bv;  break;
        default: W = Wsk; b = bsk; break;
    }
    __hip_bfloat16* out = outbase + (size_t)wsel * (size_t)N * HC;

    __shared__ float xs[BM][36];
    __shared__ float wsh[BK][132];

    const int tid = threadIdx.x;
    const int ty = tid >> 4;            // 0..15
    const int tx = tid & 15;            // 0..15
    const int rowBase = blockIdx.x * BM;

    float acc[4][8];
    #pragma unroll
    for (int i = 0; i < 4; ++i)
        #pragma unroll
        for (int j = 0; j < 8; ++j) acc[i][j] = 0.f;

    for (int k0 = 0; k0 < NIN; k0 += BK) {
        {
            const int lr = tid >> 2;          // 0..63
            const int lc = (tid & 3) * 8;     // 0,8,16,24
            const int gr = rowBase + lr;
            float4 a0 = make_float4(0.f, 0.f, 0.f, 0.f), a1 = a0;
            if (gr < N) {
                const float4* xp = (const float4*)(x + (size_t)gr * NIN + k0 + lc);
                a0 = xp[0]; a1 = xp[1];
            }
            *(float4*)&xs[lr][lc]     = a0;
            *(float4*)&xs[lr][lc + 4] = a1;
        }
        {
            const int wr = tid >> 3;          // 0..31
            const int wc = (tid & 7) * 16;    // 0..112
            const float4* wp = (const float4*)(W + (size_t)(k0 + wr) * HC + wc);
            *(float4*)&wsh[wr][wc]      = wp[0];
            *(float4*)&wsh[wr][wc + 4]  = wp[1];
            *(float4*)&wsh[wr][wc + 8]  = wp[2];
            *(float4*)&wsh[wr][wc + 12] = wp[3];
        }
        __syncthreads();

        #pragma unroll 8
        for (int kk = 0; kk < BK; ++kk) {
            float a[4];
            #pragma unroll
            for (int i = 0; i < 4; ++i) a[i] = xs[ty * 4 + i][kk];
            float4 b0 = *(float4*)&wsh[kk][tx * 8];
            float4 b1 = *(float4*)&wsh[kk][tx * 8 + 4];
            float bb[8] = {b0.x, b0.y, b0.z, b0.w, b1.x, b1.y, b1.z, b1.w};
            #pragma unroll
            for (int i = 0; i < 4; ++i)
                #pragma unroll
                for (int j = 0; j < 8; ++j)
                    acc[i][j] = fmaf(a[i], bb[j], acc[i][j]);
        }
        __syncthreads();
    }

    float bb[8];
    #pragma unroll
    for (int j = 0; j < 8; ++j) bb[j] = b[tx * 8 + j];
    #pragma unroll
    for (int i = 0; i < 4; ++i) {
        const int r = rowBase + ty * 4 + i;
        if (r < N) {
            union { __hip_bfloat16 h[8]; uint4 u; } pack;
            #pragma unroll
            for (int j = 0; j < 8; ++j)
                pack.h[j] = __float2bfloat16(acc[i][j] + bb[j]);
            *(uint4*)&out[(size_t)r * HC + tx * 8] = pack.u;
        }
    }
}

// ---------------- CSR build ----------------
__global__ __launch_bounds__(256) void hist_kernel(
    const int* __restrict__ ei, int* __restrict__ cnt, int E)
{
    const int e = blockIdx.x * 256 + threadIdx.x;
    if (e < E) atomicAdd(cnt + ei[E + e], 1);
}

// single-block hierarchical exclusive scan of cnt[0..N) -> start[], cursor[]
__global__ __launch_bounds__(1024) void scan_kernel(
    const int* __restrict__ cnt, int* __restrict__ start,
    int* __restrict__ cursor, int N)
{
    __shared__ int wsum[16];
    __shared__ int carry;
    const int tid = threadIdx.x;
    const int lane = tid & 63;
    const int w = tid >> 6;
    if (tid == 0) carry = 0;
    __syncthreads();
    for (int base = 0; base < N; base += 1024) {
        const int i = base + tid;
        const int v = (i < N) ? cnt[i] : 0;
        int x = v;                       // inclusive wave scan
        #pragma unroll
        for (int off = 1; off < 64; off <<= 1) {
            const int y = __shfl_up(x, off, 64);
            if (lane >= off) x += y;
        }
        if (lane == 63) wsum[w] = x;
        __syncthreads();
        if (w == 0 && lane < 16) {
            int y = wsum[lane];
            #pragma unroll
            for (int off = 1; off < 16; off <<= 1) {
                const int z = __shfl_up(y, off, 16);
                if (lane >= off) y += z;
            }
            wsum[lane] = y;              // inclusive over wave sums
        }
        __syncthreads();
        const int c0 = carry;
        const int excl = c0 + (w > 0 ? wsum[w - 1] : 0) + x - v;
        if (i < N) { start[i] = excl; cursor[i] = excl; }
        __syncthreads();
        if (tid == 0) carry = c0 + wsum[15];
        __syncthreads();
    }
}

__global__ __launch_bounds__(256) void scatter_kernel(
    const int* __restrict__ ei, int* __restrict__ cursor,
    int* __restrict__ csr_src, int E)
{
    const int e = blockIdx.x * 256 + threadIdx.x;
    if (e < E) {
        const int d = ei[E + e];
        const int pos = atomicAdd(cursor + d, 1);
        csr_src[pos] = ei[e];
    }
}

// ---------------- Kernel B: node-centric attention + gate + pool ----------------
// One 64-lane wave per node; lane owns channels (2*lane, 2*lane+1); head = lane>>4.
// Softmax max-shift skipped (exact identity); normalization applied after the loop.
__global__ __launch_bounds__(256) void node_aggr(
    const __hip_bfloat16* __restrict__ q, const __hip_bfloat16* __restrict__ k,
    const __hip_bfloat16* __restrict__ v, const __hip_bfloat16* __restrict__ skip,
    const int* __restrict__ start, const int* __restrict__ cnt,
    const int* __restrict__ csr_src, const float* __restrict__ Wbeta,
    const int* __restrict__ batch,
    float* __restrict__ pooled, float* __restrict__ cnts, int N)
{
    const int n = blockIdx.x * 4 + (threadIdx.x >> 6);
    if (n >= N) return;
    const int lane = threadIdx.x & 63;
    const int c = 2 * lane;

    const __hip_bfloat162 q2 = *(const __hip_bfloat162*)(q + (size_t)n * HC + c);
    const float qx = __bfloat162float(q2.x), qy = __bfloat162float(q2.y);

    const int s0 = start[n];
    const int e1 = s0 + cnt[n];
    float den = 0.f, a0 = 0.f, a1 = 0.f;
    int s = (s0 < e1) ? csr_src[s0] : 0;
    for (int i = s0; i < e1; ++i) {
        const int snext = (i + 1 < e1) ? csr_src[i + 1] : 0;
        const __hip_bfloat162 k2 = *(const __hip_bfloat162*)(k + (size_t)s * HC + c);
        const __hip_bfloat162 v2 = *(const __hip_bfloat162*)(v + (size_t)s * HC + c);
        float p = qx * __bfloat162float(k2.x) + qy * __bfloat162float(k2.y);
        p += __shfl_xor(p, 1, 64);
        p += __shfl_xor(p, 2, 64);
        p += __shfl_xor(p, 4, 64);
        p += __shfl_xor(p, 8, 64);
        const float ex = __expf(p * 0.17677669529663687f);   // 1/sqrt(32)
        den += ex;
        a0 = fmaf(__bfloat162float(v2.x), ex, a0);
        a1 = fmaf(__bfloat162float(v2.y), ex, a1);
        s = snext;
    }
    const float inv = 1.f / (den + 1e-16f);
    const float o0 = a0 * inv, o1 = a1 * inv;

    const __hip_bfloat162 s2 = *(const __hip_bfloat162*)(skip + (size_t)n * HC + c);
    const float sk0 = __bfloat162float(s2.x);
    const float sk1 = __bfloat162float(s2.y);

    float part = o0 * Wbeta[c]     + sk0 * Wbeta[HC + c]     + (o0 - sk0) * Wbeta[2 * HC + c]
               + o1 * Wbeta[c + 1] + sk1 * Wbeta[HC + c + 1] + (o1 - sk1) * Wbeta[2 * HC + c + 1];
    #pragma unroll
    for (int m = 1; m < 64; m <<= 1) part += __shfl_xor(part, m, 64);

    const float beta = 1.f / (1.f + __expf(-part));
    float r0 = beta * sk0 + (1.f - beta) * o0;
    float r1 = beta * sk1 + (1.f - beta) * o1;
    r0 = (r0 >= 0.f) ? r0 : 0.01f * r0;
    r1 = (r1 >= 0.f) ? r1 : 0.01f * r1;

    const int g = batch[n];
    atomicAdd(pooled + (size_t)g * HC + c,     r0);
    atomicAdd(pooled + (size_t)g * HC + c + 1, r1);
    if (lane == 0) atomicAdd(cnts + g, 1.0f);
}

// ---------------- Kernel D: per-graph mean + final GEMM ----------------
__global__ __launch_bounds__(256) void final_gemm(
    const float* __restrict__ pooled, const float* __restrict__ cnts,
    const float* __restrict__ W2, const float* __restrict__ b2,
    float* __restrict__ out, int G)
{
    const int g = blockIdx.x;
    __shared__ float p[HC];
    const int t = threadIdx.x;
    if (t < HC) p[t] = pooled[(size_t)g * HC + t] / fmaxf(cnts[g], 1.0f);
    __syncthreads();
    for (int j = t; j < NOUT; j += 256) {
        float acc = b2[j];
        #pragma unroll 8
        for (int c = 0; c < HC; ++c) acc = fmaf(p[c], W2[(size_t)c * NOUT + j], acc);
        out[(size_t)g * NOUT + j] = acc;
    }
}

// ---------------- launch ----------------
extern "C" void kernel_launch(void* const* d_in, const int* in_sizes, int n_in,
                              void* d_out, int out_size, void* d_ws, size_t ws_size,
                              hipStream_t stream) {
    const float* x     = (const float*)d_in[0];
    const int*   ei    = (const int*)d_in[1];
    const int*   batch = (const int*)d_in[2];
    const float* Wq  = (const float*)d_in[3];  const float* bq  = (const float*)d_in[4];
    const float* Wk  = (const float*)d_in[5];  const float* bk  = (const float*)d_in[6];
    const float* Wv  = (const float*)d_in[7];  const float* bv  = (const float*)d_in[8];
    const float* Wsk = (const float*)d_in[9];  const float* bsk = (const float*)d_in[10];
    const float* Wbeta = (const float*)d_in[11];
    const float* W2  = (const float*)d_in[12]; const float* b2  = (const float*)d_in[13];

    const int N = in_sizes[0] / NIN;
    const int E = in_sizes[1] / 2;
    const int G = out_size / NOUT;

    char* ws = (char*)d_ws;
    const size_t nbQ = (size_t)N * HC * sizeof(__hip_bfloat16);
    __hip_bfloat16* q    = (__hip_bfloat16*)(ws);
    __hip_bfloat16* kk_  = (__hip_bfloat16*)(ws + nbQ);
    __hip_bfloat16* vv   = (__hip_bfloat16*)(ws + 2 * nbQ);
    __hip_bfloat16* skip = (__hip_bfloat16*)(ws + 3 * nbQ);
    int* cnt    = (int*)(ws + 4 * nbQ);
    int* start  = cnt + N;
    int* cursor = start + N;
    int* csr    = cursor + N;
    float* pooled = (float*)(csr + E);
    float* cnts   = pooled + (size_t)G * HC;

    // zero: cnt, then pooled+cnts (contiguous)
    hipMemsetAsync(cnt, 0, (size_t)N * sizeof(int), stream);
    hipMemsetAsync(pooled, 0, ((size_t)G * HC + G) * sizeof(float), stream);

    // CSR build
    const int eb = (E + 255) / 256;
    hist_kernel<<<eb, 256, 0, stream>>>(ei, cnt, E);
    scan_kernel<<<1, 1024, 0, stream>>>(cnt, start, cursor, N);
    scatter_kernel<<<eb, 256, 0, stream>>>(ei, cursor, csr, E);

    // projections
    dim3 gA((N + BM - 1) / BM, 4);
    gemm_qkvs<<<gA, 256, 0, stream>>>(x, Wq, bq, Wk, bk, Wv, bv, Wsk, bsk, q, N);

    // node-centric attention + gate + pool
    node_aggr<<<(N + 3) / 4, 256, 0, stream>>>(q, kk_, vv, skip, start, cnt, csr,
                                               Wbeta, batch, pooled, cnts, N);

    // mean + final projection
    final_gemm<<<G, 256, 0, stream>>>(pooled, cnts, W2, b2, (float*)d_out, G);
}

// Round 4
// 352.204 us; speedup vs baseline: 3.0968x; 1.6954x over previous
//
#include <hip/hip_runtime.h>
#include <hip/hip_bf16.h>
#include <math.h>

#define NIN 128
#define HC 128
#define NOUT 768

typedef __attribute__((ext_vector_type(8))) short bf16x8;
typedef __attribute__((ext_vector_type(4))) float f32x4;
typedef __attribute__((ext_vector_type(4))) unsigned short ushort4v;
typedef __attribute__((ext_vector_type(8))) unsigned short ushort8v;

__device__ __forceinline__ unsigned short f2bf(float f) {
    __hip_bfloat16 h = __float2bfloat16(f);
    return *(unsigned short*)&h;
}

// ---------------- prep: W[k][n] fp32 -> Wt[n][k] bf16 (4 weights) ----------------
__global__ __launch_bounds__(256) void prep_w(
    const float* __restrict__ Wq, const float* __restrict__ Wk,
    const float* __restrict__ Wv, const float* __restrict__ Wsk,
    unsigned short* __restrict__ Wtb)
{
    const float* W = (blockIdx.x == 0) ? Wq : (blockIdx.x == 1) ? Wk
                   : (blockIdx.x == 2) ? Wv : Wsk;
    unsigned short* out = Wtb + (size_t)blockIdx.x * 128 * 128;
    const int t = threadIdx.x;
    for (int s = 0; s < 16; ++s) {
        const int f = t + s * 256;           // float4 index (4096 total)
        const int k = f >> 5;
        const int n = (f & 31) * 4;
        float4 w4 = *(const float4*)(W + (size_t)k * 128 + n);
        out[(size_t)(n    ) * 128 + k] = f2bf(w4.x);
        out[(size_t)(n + 1) * 128 + k] = f2bf(w4.y);
        out[(size_t)(n + 2) * 128 + k] = f2bf(w4.z);
        out[(size_t)(n + 3) * 128 + k] = f2bf(w4.w);
    }
}

// ---------------- Kernel A: MFMA projections, all 4 weights per block ----------------
__global__ __launch_bounds__(256) void gemm4_mfma(
    const float* __restrict__ x, const unsigned short* __restrict__ Wtb,
    const float* __restrict__ bq, const float* __restrict__ bk,
    const float* __restrict__ bv, const float* __restrict__ bsk,
    __hip_bfloat16* __restrict__ outbase, int N)
{
    __shared__ unsigned short At[128][136];   // A[row][k], 2-way max bank alias
    __shared__ unsigned short Bt[128][136];   // B^T[n][k]
    const int tid = threadIdx.x;
    const int lane = tid & 63;
    const int wave = tid >> 6;
    const int rowBase = blockIdx.x * 128;

    // stage A: x fp32 -> bf16 LDS (fully coalesced float4 reads)
    #pragma unroll
    for (int s = 0; s < 16; ++s) {
        const int f = tid + s * 256;          // float4 idx
        const int r = f >> 5;
        const int cl = (f & 31) * 4;
        const int gr = rowBase + r;
        float4 a4 = make_float4(0.f, 0.f, 0.f, 0.f);
        if (gr < N) a4 = *(const float4*)(x + (size_t)gr * 128 + cl);
        ushort4v u;
        u.x = f2bf(a4.x); u.y = f2bf(a4.y); u.z = f2bf(a4.z); u.w = f2bf(a4.w);
        *(ushort4v*)&At[r][cl] = u;
    }

    bf16x8 afr[2][4];
    bool afr_loaded = false;

    for (int w = 0; w < 4; ++w) {
        // stage Bt for weight w (bf16, coalesced 16B reads)
        const unsigned short* Wp = Wtb + (size_t)w * 128 * 128;
        #pragma unroll
        for (int s = 0; s < 8; ++s) {
            const int f = tid + s * 256;      // ushort8 idx (2048 total)
            const int n = f >> 4;
            const int kc = (f & 15) * 8;
            *(ushort8v*)&Bt[n][kc] = *(const ushort8v*)(Wp + (size_t)n * 128 + kc);
        }
        __syncthreads();

        if (!afr_loaded) {
            afr_loaded = true;
            #pragma unroll
            for (int m = 0; m < 2; ++m)
                #pragma unroll
                for (int kk = 0; kk < 4; ++kk)
                    afr[m][kk] = *(bf16x8*)&At[wave * 32 + m * 16 + (lane & 15)]
                                            [kk * 32 + (lane >> 4) * 8];
        }

        const float* bias = (w == 0) ? bq : (w == 1) ? bk : (w == 2) ? bv : bsk;
        __hip_bfloat16* out = outbase + (size_t)w * (size_t)N * 128;

        f32x4 acc[2][8];
        #pragma unroll
        for (int m = 0; m < 2; ++m)
            #pragma unroll
            for (int nr = 0; nr < 8; ++nr)
                acc[m][nr] = (f32x4){0.f, 0.f, 0.f, 0.f};

        #pragma unroll
        for (int nr = 0; nr < 8; ++nr) {
            bf16x8 bfr[4];
            #pragma unroll
            for (int kk = 0; kk < 4; ++kk)
                bfr[kk] = *(bf16x8*)&Bt[nr * 16 + (lane & 15)]
                                       [kk * 32 + (lane >> 4) * 8];
            #pragma unroll
            for (int kk = 0; kk < 4; ++kk) {
                #pragma unroll
                for (int m = 0; m < 2; ++m)
                    acc[m][nr] = __builtin_amdgcn_mfma_f32_16x16x32_bf16(
                        afr[m][kk], bfr[kk], acc[m][nr], 0, 0, 0);
            }
        }

        // store: C/D layout col = lane&15, row = (lane>>4)*4 + j
        const int colb = lane & 15;
        #pragma unroll
        for (int nr = 0; nr < 8; ++nr) {
            const int col = nr * 16 + colb;
            const float bb = bias[col];
            #pragma unroll
            for (int m = 0; m < 2; ++m) {
                #pragma unroll
                for (int j = 0; j < 4; ++j) {
                    const int r = rowBase + wave * 32 + m * 16 + (lane >> 4) * 4 + j;
                    if (r < N)
                        out[(size_t)r * 128 + col] = __float2bfloat16(acc[m][nr][j] + bb);
                }
            }
        }
        __syncthreads();   // before overwriting Bt
    }
}

// ---------------- CSR build ----------------
__global__ __launch_bounds__(256) void hist_kernel(
    const int* __restrict__ ei, int* __restrict__ cnt, int E)
{
    const int e = blockIdx.x * 256 + threadIdx.x;
    if (e < E) atomicAdd(cnt + ei[E + e], 1);
}

__global__ __launch_bounds__(1024) void scan_part(
    const int* __restrict__ cnt, int* __restrict__ start,
    int* __restrict__ bsum, int N)
{
    __shared__ int wsum[16];
    const int tid = threadIdx.x;
    const int lane = tid & 63;
    const int w = tid >> 6;
    const int i = blockIdx.x * 1024 + tid;
    const int v = (i < N) ? cnt[i] : 0;
    int xv = v;
    #pragma unroll
    for (int off = 1; off < 64; off <<= 1) {
        const int y = __shfl_up(xv, off, 64);
        if (lane >= off) xv += y;
    }
    if (lane == 63) wsum[w] = xv;
    __syncthreads();
    if (tid < 16) {
        int y = wsum[tid];
        #pragma unroll
        for (int off = 1; off < 16; off <<= 1) {
            const int z = __shfl_up(y, off, 64);
            if (tid >= off) y += z;
        }
        wsum[tid] = y;
    }
    __syncthreads();
    const int excl = (w > 0 ? wsum[w - 1] : 0) + xv - v;
    if (i < N) start[i] = excl;
    if (tid == 1023) bsum[blockIdx.x] = wsum[15];
}

__global__ __launch_bounds__(128) void scan_bsum(int* __restrict__ bsum, int NB)
{
    const int tid = threadIdx.x;
    __shared__ int w0tot;
    const int v = (tid < NB) ? bsum[tid] : 0;
    int xv = v;
    const int lane = tid & 63;
    #pragma unroll
    for (int off = 1; off < 64; off <<= 1) {
        const int y = __shfl_up(xv, off, 64);
        if (lane >= off) xv += y;
    }
    if (tid == 63) w0tot = xv;
    __syncthreads();
    const int incl = xv + ((tid >= 64) ? w0tot : 0);
    if (tid < NB) bsum[tid] = incl - v;     // exclusive
}

__global__ __launch_bounds__(256) void scan_add(
    int* __restrict__ start, int* __restrict__ cursor,
    const int* __restrict__ bsum, int N)
{
    const int i = blockIdx.x * 256 + threadIdx.x;
    if (i < N) {
        const int s = start[i] + bsum[i >> 10];
        start[i] = s;
        cursor[i] = s;
    }
}

__global__ __launch_bounds__(256) void scatter_kernel(
    const int* __restrict__ ei, int* __restrict__ cursor,
    int* __restrict__ csr_src, int E)
{
    const int e = blockIdx.x * 256 + threadIdx.x;
    if (e < E) {
        const int d = ei[E + e];
        const int pos = atomicAdd(cursor + d, 1);
        csr_src[pos] = ei[e];
    }
}

// ---------------- Kernel B: node-centric attention + gate (no atomics) ----------------
__global__ __launch_bounds__(256) void node_aggr(
    const __hip_bfloat16* __restrict__ q, const __hip_bfloat16* __restrict__ k,
    const __hip_bfloat16* __restrict__ v, const __hip_bfloat16* __restrict__ skip,
    const int* __restrict__ start, const int* __restrict__ cnt,
    const int* __restrict__ csr_src, const float* __restrict__ Wbeta,
    __hip_bfloat16* __restrict__ gout, int N)
{
    const int n = blockIdx.x * 4 + (threadIdx.x >> 6);
    if (n >= N) return;
    const int lane = threadIdx.x & 63;
    const int c = 2 * lane;
    const float scale = 0.17677669529663687f;   // 1/sqrt(32)

    const __hip_bfloat162 q2 = *(const __hip_bfloat162*)(q + (size_t)n * HC + c);
    const float qx = __bfloat162float(q2.x), qy = __bfloat162float(q2.y);

    const int s0 = start[n];
    const int e1 = s0 + cnt[n];
    float den = 0.f, a0 = 0.f, a1 = 0.f;
    int i = s0;
    for (; i + 1 < e1; i += 2) {
        const int sa = csr_src[i];
        const int sb = csr_src[i + 1];
        const __hip_bfloat162 k2a = *(const __hip_bfloat162*)(k + (size_t)sa * HC + c);
        const __hip_bfloat162 v2a = *(const __hip_bfloat162*)(v + (size_t)sa * HC + c);
        const __hip_bfloat162 k2b = *(const __hip_bfloat162*)(k + (size_t)sb * HC + c);
        const __hip_bfloat162 v2b = *(const __hip_bfloat162*)(v + (size_t)sb * HC + c);
        float pa = qx * __bfloat162float(k2a.x) + qy * __bfloat162float(k2a.y);
        float pb = qx * __bfloat162float(k2b.x) + qy * __bfloat162float(k2b.y);
        #pragma unroll
        for (int m = 1; m < 16; m <<= 1) {
            pa += __shfl_xor(pa, m, 64);
            pb += __shfl_xor(pb, m, 64);
        }
        const float exa = __expf(pa * scale);
        const float exb = __expf(pb * scale);
        den += exa + exb;
        a0 = fmaf(__bfloat162float(v2a.x), exa, fmaf(__bfloat162float(v2b.x), exb, a0));
        a1 = fmaf(__bfloat162float(v2a.y), exa, fmaf(__bfloat162float(v2b.y), exb, a1));
    }
    if (i < e1) {
        const int sa = csr_src[i];
        const __hip_bfloat162 k2a = *(const __hip_bfloat162*)(k + (size_t)sa * HC + c);
        const __hip_bfloat162 v2a = *(const __hip_bfloat162*)(v + (size_t)sa * HC + c);
        float pa = qx * __bfloat162float(k2a.x) + qy * __bfloat162float(k2a.y);
        #pragma unroll
        for (int m = 1; m < 16; m <<= 1) pa += __shfl_xor(pa, m, 64);
        const float exa = __expf(pa * scale);
        den += exa;
        a0 = fmaf(__bfloat162float(v2a.x), exa, a0);
        a1 = fmaf(__bfloat162float(v2a.y), exa, a1);
    }

    const float inv = 1.f / (den + 1e-16f);
    const float o0 = a0 * inv, o1 = a1 * inv;

    const __hip_bfloat162 s2 = *(const __hip_bfloat162*)(skip + (size_t)n * HC + c);
    const float sk0 = __bfloat162float(s2.x);
    const float sk1 = __bfloat162float(s2.y);

    float part = o0 * Wbeta[c]     + sk0 * Wbeta[HC + c]     + (o0 - sk0) * Wbeta[2 * HC + c]
               + o1 * Wbeta[c + 1] + sk1 * Wbeta[HC + c + 1] + (o1 - sk1) * Wbeta[2 * HC + c + 1];
    #pragma unroll
    for (int m = 1; m < 64; m <<= 1) part += __shfl_xor(part, m, 64);

    const float beta = 1.f / (1.f + __expf(-part));
    float r0 = beta * sk0 + (1.f - beta) * o0;
    float r1 = beta * sk1 + (1.f - beta) * o1;
    r0 = (r0 >= 0.f) ? r0 : 0.01f * r0;
    r1 = (r1 >= 0.f) ? r1 : 0.01f * r1;

    __hip_bfloat162 g2;
    g2.x = __float2bfloat16(r0);
    g2.y = __float2bfloat16(r1);
    *(__hip_bfloat162*)(gout + (size_t)n * HC + c) = g2;
}

// ---------------- pool per graph (batch is sorted; binary search the range) ----------------
__global__ __launch_bounds__(128) void pool_graph(
    const __hip_bfloat16* __restrict__ gout, const int* __restrict__ batch,
    float* __restrict__ pooled, int N)
{
    const int g = blockIdx.x;
    const int t = threadIdx.x;
    int lo = 0, hi = N;
    while (lo < hi) { const int m = (lo + hi) >> 1; if (batch[m] < g) lo = m + 1; else hi = m; }
    int lo2 = lo, hi2 = N;
    while (lo2 < hi2) { const int m = (lo2 + hi2) >> 1; if (batch[m] < g + 1) lo2 = m + 1; else hi2 = m; }
    float acc = 0.f;
    for (int r = lo; r < lo2; ++r)
        acc += __bfloat162float(gout[(size_t)r * HC + t]);
    pooled[(size_t)g * HC + t] = acc / fmaxf((float)(lo2 - lo), 1.f);
}

// ---------------- final GEMM ----------------
__global__ __launch_bounds__(256) void final_gemm(
    const float* __restrict__ pooled,
    const float* __restrict__ W2, const float* __restrict__ b2,
    float* __restrict__ out, int G)
{
    const int g = blockIdx.x;
    __shared__ float p[HC];
    const int t = threadIdx.x;
    if (t < HC) p[t] = pooled[(size_t)g * HC + t];
    __syncthreads();
    for (int j = t; j < NOUT; j += 256) {
        float acc = b2[j];
        #pragma unroll 8
        for (int c = 0; c < HC; ++c) acc = fmaf(p[c], W2[(size_t)c * NOUT + j], acc);
        out[(size_t)g * NOUT + j] = acc;
    }
}

// ---------------- launch ----------------
extern "C" void kernel_launch(void* const* d_in, const int* in_sizes, int n_in,
                              void* d_out, int out_size, void* d_ws, size_t ws_size,
                              hipStream_t stream) {
    const float* x     = (const float*)d_in[0];
    const int*   ei    = (const int*)d_in[1];
    const int*   batch = (const int*)d_in[2];
    const float* Wq  = (const float*)d_in[3];  const float* bq  = (const float*)d_in[4];
    const float* Wk  = (const float*)d_in[5];  const float* bk  = (const float*)d_in[6];
    const float* Wv  = (const float*)d_in[7];  const float* bv  = (const float*)d_in[8];
    const float* Wsk = (const float*)d_in[9];  const float* bsk = (const float*)d_in[10];
    const float* Wbeta = (const float*)d_in[11];
    const float* W2  = (const float*)d_in[12]; const float* b2  = (const float*)d_in[13];

    const int N = in_sizes[0] / NIN;
    const int E = in_sizes[1] / 2;
    const int G = out_size / NOUT;

    char* ws = (char*)d_ws;
    const size_t nbQ = (size_t)N * HC * sizeof(__hip_bfloat16);
    __hip_bfloat16* q    = (__hip_bfloat16*)(ws);
    __hip_bfloat16* kk_  = (__hip_bfloat16*)(ws + nbQ);
    __hip_bfloat16* vv   = (__hip_bfloat16*)(ws + 2 * nbQ);
    __hip_bfloat16* skip = (__hip_bfloat16*)(ws + 3 * nbQ);
    char* p0 = ws + 4 * nbQ;
    unsigned short* Wtb = (unsigned short*)p0;            p0 += 4 * 128 * 128 * sizeof(unsigned short);
    int* cnt    = (int*)p0;                               p0 += (size_t)N * sizeof(int);
    int* start  = (int*)p0;                               p0 += (size_t)N * sizeof(int);
    int* cursor = (int*)p0;                               p0 += (size_t)N * sizeof(int);
    int* bsum   = (int*)p0;                               p0 += 1024 * sizeof(int);
    int* csr    = (int*)p0;                               p0 += (size_t)E * sizeof(int);
    __hip_bfloat16* gout = (__hip_bfloat16*)p0;           p0 += nbQ;
    float* pooled = (float*)p0;

    hipMemsetAsync(cnt, 0, (size_t)N * sizeof(int), stream);

    const int eb = (E + 255) / 256;
    const int NB = (N + 1023) / 1024;
    hist_kernel<<<eb, 256, 0, stream>>>(ei, cnt, E);
    scan_part<<<NB, 1024, 0, stream>>>(cnt, start, bsum, N);
    scan_bsum<<<1, 128, 0, stream>>>(bsum, NB);
    scan_add<<<(N + 255) / 256, 256, 0, stream>>>(start, cursor, bsum, N);
    scatter_kernel<<<eb, 256, 0, stream>>>(ei, cursor, csr, E);

    prep_w<<<4, 256, 0, stream>>>(Wq, Wk, Wv, Wsk, Wtb);
    gemm4_mfma<<<(N + 127) / 128, 256, 0, stream>>>(x, Wtb, bq, bk, bv, bsk, q, N);

    node_aggr<<<(N + 3) / 4, 256, 0, stream>>>(q, kk_, vv, skip, start, cnt, csr,
                                               Wbeta, gout, N);

    pool_graph<<<G, 128, 0, stream>>>(gout, batch, pooled, N);
    final_gemm<<<G, 256, 0, stream>>>(pooled, W2, b2, (float*)d_out, G);
}